// Round 5
// baseline (49.653 us; speedup 1.0000x reference)
//
#include <hip/hip_runtime.h>

#define KS    7
#define RAD   3
#define TS    32            // tile is 32x32 output px
#define HALO  38            // TS + 2*RAD
#define NT    (HALO*HALO)   // 1444 staging sites
#define PITCH 43            // physical row stride in 16B units (max swz(37)=41, odd-ish pad)
#define H     256
#define W     256
#define HWp   (H*W)

typedef __fp16 h2v __attribute__((ext_vector_type(2)));
typedef __fp16 h8v __attribute__((ext_vector_type(8)));

// skew: spreads stride-2 16B reads across all 8 4-bank groups
__device__ __forceinline__ int swz(int c) { return c + (c >> 3); }

__device__ __forceinline__ unsigned pk(float a, float b) {
    h2v h = __builtin_amdgcn_cvt_pkrtz(a, b);
    return __builtin_bit_cast(unsigned, h);
}

__global__ __launch_bounds__(256, 2)
void bilateral_kernel(const float* __restrict__ in,      // [B][32][H][W]
                      const float* __restrict__ guide,   // [B][3][H][W]
                      const float* __restrict__ sigma_p, // [1]
                      float* __restrict__ out)           // [B][32][H][W]
{
    __shared__ float4 gtile[HALO * PITCH];   // guide: 3ch f32 per px
    __shared__ uint4  itile[HALO * PITCH];   // input: 8ch fp16 per px

    const int tid   = threadIdx.x;
    const int tx    = tid & 15;              // x-pair index (0..15)
    const int ty    = tid >> 4;              // y-pair index (0..15)
    const int x0    = blockIdx.x * TS;
    const int y0    = blockIdx.y * TS;
    const int b     = blockIdx.z >> 2;       // batch
    const int cg0   = (blockIdx.z & 3) * 8;  // this block's 8 channels

    const float* gb  = guide + (size_t)b * 3 * HWp;
    const float* inb = in    + ((size_t)b * 32 + cg0) * HWp;

    const float sigma  = sigma_p[0];
    const float inv2s2 = 0.5f / (sigma * sigma);
    float eT[KS];
#pragma unroll
    for (int i = 0; i < KS; ++i) {
        float r = (float)(i - RAD);
        eT[i] = __expf(-r * r * inv2s2);
    }

    // ---- stage guide (f32) + input (8ch fp16) tiles, zero halo, skewed ----
#pragma unroll
    for (int it = 0; it < 6; ++it) {
        int idx = tid + it * 256;
        if (idx < NT) {
            int row = idx / HALO;
            int col = idx - row * HALO;
            int gy = y0 - RAD + row, gx = x0 - RAD + col;
            float4 gv = make_float4(0.f, 0.f, 0.f, 0.f);
            uint4  pv = make_uint4(0u, 0u, 0u, 0u);
            if (gy >= 0 && gy < H && gx >= 0 && gx < W) {
                int off = gy * W + gx;
                gv.x = gb[off]; gv.y = gb[HWp + off]; gv.z = gb[2 * HWp + off];
                float v0 = inb[off],           v1 = inb[HWp + off];
                float v2 = inb[2 * HWp + off], v3 = inb[3 * HWp + off];
                float v4 = inb[4 * HWp + off], v5 = inb[5 * HWp + off];
                float v6 = inb[6 * HWp + off], v7 = inb[7 * HWp + off];
                pv.x = pk(v0, v1); pv.y = pk(v2, v3);
                pv.z = pk(v4, v5); pv.w = pk(v6, v7);
            }
            int a = row * PITCH + swz(col);
            gtile[a] = gv;
            itile[a] = pv;
        }
    }
    __syncthreads();

    // ---- centers for the 2x2 pixels this thread owns ----
    const float4 c00 = gtile[(2 * ty + 3) * PITCH + swz(2 * tx + 3)];
    const float4 c01 = gtile[(2 * ty + 3) * PITCH + swz(2 * tx + 4)];
    const float4 c10 = gtile[(2 * ty + 4) * PITCH + swz(2 * tx + 3)];
    const float4 c11 = gtile[(2 * ty + 4) * PITCH + swz(2 * tx + 4)];

    float n00 = 0.f, n01 = 0.f, n10 = 0.f, n11 = 0.f;
    float a00[8], a01[8], a10[8], a11[8];
#pragma unroll
    for (int c = 0; c < 8; ++c) { a00[c] = a01[c] = a10[c] = a11[c] = 0.f; }

    // ---- fused weight+apply: 8 window rows serve both y-pixels ----
#pragma unroll
    for (int i = 0; i < 8; ++i) {
        float4 g[8];
        uint4  rq[8];
#pragma unroll
        for (int k = 0; k < 8; ++k) {
            int a = (2 * ty + i) * PITCH + swz(2 * tx + k);
            g[k]  = gtile[a];
            rq[k] = itile[a];
        }
        float rv[8][8];
#pragma unroll
        for (int k = 0; k < 8; ++k) {
            h8v hv = __builtin_bit_cast(h8v, rq[k]);
#pragma unroll
            for (int c = 0; c < 8; ++c) rv[k][c] = (float)hv[c];
        }
#pragma unroll
        for (int dj = 0; dj < KS; ++dj) {
            if (i < 7) {                       // y-pixel 0, tap row di=i
                float E = eT[i] * eT[dj];
                float dx = g[dj].x - c00.x, dy = g[dj].y - c00.y, dz = g[dj].z - c00.z;
                float w = E * __expf(-0.5f * (dx * dx + dy * dy + dz * dz));
                n00 += w;
#pragma unroll
                for (int c = 0; c < 8; ++c) a00[c] += w * rv[dj][c];
                dx = g[dj + 1].x - c01.x; dy = g[dj + 1].y - c01.y; dz = g[dj + 1].z - c01.z;
                w = E * __expf(-0.5f * (dx * dx + dy * dy + dz * dz));
                n01 += w;
#pragma unroll
                for (int c = 0; c < 8; ++c) a01[c] += w * rv[dj + 1][c];
            }
            if (i > 0) {                       // y-pixel 1, tap row di=i-1
                float E = eT[i - 1] * eT[dj];
                float dx = g[dj].x - c10.x, dy = g[dj].y - c10.y, dz = g[dj].z - c10.z;
                float w = E * __expf(-0.5f * (dx * dx + dy * dy + dz * dz));
                n10 += w;
#pragma unroll
                for (int c = 0; c < 8; ++c) a10[c] += w * rv[dj][c];
                dx = g[dj + 1].x - c11.x; dy = g[dj + 1].y - c11.y; dz = g[dj + 1].z - c11.z;
                w = E * __expf(-0.5f * (dx * dx + dy * dy + dz * dz));
                n11 += w;
#pragma unroll
                for (int c = 0; c < 8; ++c) a11[c] += w * rv[dj + 1][c];
            }
        }
    }

    // ---- normalize + store (norm >= center weight = 1, never 0) ----
    const float i00 = 1.f / n00, i01 = 1.f / n01;
    const float i10 = 1.f / n10, i11 = 1.f / n11;
    const int X = x0 + 2 * tx, Y = y0 + 2 * ty;
    float* ob = out + ((size_t)b * 32 + cg0) * HWp + (size_t)Y * W + X;
#pragma unroll
    for (int c = 0; c < 8; ++c) {
        float2 s0, s1;
        s0.x = a00[c] * i00; s0.y = a01[c] * i01;
        s1.x = a10[c] * i10; s1.y = a11[c] * i11;
        *(float2*)(ob + (size_t)c * HWp)     = s0;
        *(float2*)(ob + (size_t)c * HWp + W) = s1;
    }
}

extern "C" void kernel_launch(void* const* d_in, const int* in_sizes, int n_in,
                              void* d_out, int out_size, void* d_ws, size_t ws_size,
                              hipStream_t stream) {
    const float* in    = (const float*)d_in[0];
    const float* guide = (const float*)d_in[1];
    const float* sigma = (const float*)d_in[2];
    float* out = (float*)d_out;
    dim3 grid(W / TS, H / TS, 2 * 4);   // z = batch*4 + channel-quarter
    bilateral_kernel<<<grid, dim3(256), 0, stream>>>(in, guide, sigma, out);
}

// Round 6
// 31.218 us; speedup vs baseline: 1.5905x; 1.5905x over previous
//
#include <hip/hip_runtime.h>

#define KS    7
#define RAD   3
#define TW    32            // tile width (output px)
#define TH    16            // tile height
#define HC    38            // TW + 2*RAD
#define HR    22            // TH + 2*RAD
#define NT    (HR*HC)       // 836 staging sites
#define PITCH 43            // physical row stride in 16B units (max swz(37)=41, +pad)
#define H     256
#define W     256
#define HWp   (H*W)

typedef __fp16 h2v __attribute__((ext_vector_type(2)));
typedef __fp16 h8v __attribute__((ext_vector_type(8)));

// skew: spreads stride-2 16B reads across all 8 4-bank groups (8 req/group/wave = minimal)
__device__ __forceinline__ int swz(int c) { return c + (c >> 3); }

__device__ __forceinline__ unsigned pk(float a, float b) {
    h2v h = __builtin_amdgcn_cvt_pkrtz(a, b);
    return __builtin_bit_cast(unsigned, h);
}

__device__ __forceinline__ void conv8(uint4 q, float* r) {
    h8v hv = __builtin_bit_cast(h8v, q);
#pragma unroll
    for (int c = 0; c < 8; ++c) r[c] = (float)hv[c];
}

__global__ __launch_bounds__(256, 3)
void bilateral_kernel(const float* __restrict__ in,      // [B][32][H][W]
                      const float* __restrict__ guide,   // [B][3][H][W]
                      const float* __restrict__ sigma_p, // [1]
                      float* __restrict__ out)           // [B][32][H][W]
{
    __shared__ float4 gt[HR * PITCH];    // guide: 3ch f32 per px
    __shared__ uint4  dt[HR * PITCH];    // input: 8ch fp16 per px

    const int tid = threadIdx.x;
    const int tx  = tid & 15;            // x-pair index
    const int ty  = tid >> 4;            // y row (0..15)
    const int x0  = blockIdx.x * TW;
    const int y0  = blockIdx.y * TH;
    const int b   = blockIdx.z >> 2;     // batch
    const int cg0 = (blockIdx.z & 3) * 8;

    const float* gb  = guide + (size_t)b * 3 * HWp;
    const float* inb = in    + ((size_t)b * 32 + cg0) * HWp;

    const float sigma  = sigma_p[0];
    const float inv2s2 = 0.5f / (sigma * sigma);
    float eT[KS];
#pragma unroll
    for (int i = 0; i < KS; ++i) {
        float r = (float)(i - RAD);
        eT[i] = __expf(-r * r * inv2s2);
    }

    // ---- stage guide (f32) + input (8ch fp16) tiles, zero halo, skewed ----
#pragma unroll
    for (int it = 0; it < 4; ++it) {
        int idx = tid + it * 256;
        if (idx < NT) {
            int row = idx / HC;
            int col = idx - row * HC;
            int gy = y0 - RAD + row, gx = x0 - RAD + col;
            float4 gv = make_float4(0.f, 0.f, 0.f, 0.f);
            uint4  pv = make_uint4(0u, 0u, 0u, 0u);
            if (gy >= 0 && gy < H && gx >= 0 && gx < W) {
                int off = gy * W + gx;
                gv.x = gb[off]; gv.y = gb[HWp + off]; gv.z = gb[2 * HWp + off];
                float v0 = inb[off],           v1 = inb[HWp + off];
                float v2 = inb[2 * HWp + off], v3 = inb[3 * HWp + off];
                float v4 = inb[4 * HWp + off], v5 = inb[5 * HWp + off];
                float v6 = inb[6 * HWp + off], v7 = inb[7 * HWp + off];
                pv.x = pk(v0, v1); pv.y = pk(v2, v3);
                pv.z = pk(v4, v5); pv.w = pk(v6, v7);
            }
            int a = row * PITCH + swz(col);
            gt[a] = gv;
            dt[a] = pv;
        }
    }
    __syncthreads();

    // ---- centers for this thread's 2 pixels ----
    const float4 c0 = gt[(ty + RAD) * PITCH + swz(2 * tx + 3)];
    const float4 c1 = gt[(ty + RAD) * PITCH + swz(2 * tx + 4)];

    float n0 = 0.f, n1 = 0.f;
    float a0[8], a1[8];
#pragma unroll
    for (int c = 0; c < 8; ++c) { a0[c] = 0.f; a1[c] = 0.f; }

    // ---- fused weight+apply, rolling 2-column fp16->f32 conversion ----
#pragma unroll
    for (int i = 0; i < KS; ++i) {
        const int base = (ty + i) * PITCH;
        float4 g[8];
        uint4  rq[8];
#pragma unroll
        for (int k = 0; k < 8; ++k) {
            int a = base + swz(2 * tx + k);
            g[k]  = gt[a];
            rq[k] = dt[a];
        }
        float rvA[8], rvB[8];
        conv8(rq[0], rvA);
#pragma unroll
        for (int dj = 0; dj < KS; ++dj) {
            conv8(rq[dj + 1], rvB);
            const float E = eT[i] * eT[dj];
            // pixel 0: window col dj
            float dx = g[dj].x - c0.x, dy = g[dj].y - c0.y, dz = g[dj].z - c0.z;
            float w0 = E * __expf(-0.5f * (dx * dx + dy * dy + dz * dz));
            n0 += w0;
#pragma unroll
            for (int c = 0; c < 8; ++c) a0[c] += w0 * rvA[c];
            // pixel 1: window col dj+1
            dx = g[dj + 1].x - c1.x; dy = g[dj + 1].y - c1.y; dz = g[dj + 1].z - c1.z;
            float w1 = E * __expf(-0.5f * (dx * dx + dy * dy + dz * dz));
            n1 += w1;
#pragma unroll
            for (int c = 0; c < 8; ++c) a1[c] += w1 * rvB[c];
            // roll: col dj+1 becomes next iteration's col dj (SSA rename, no real moves)
#pragma unroll
            for (int c = 0; c < 8; ++c) rvA[c] = rvB[c];
        }
    }

    // ---- normalize + store (norm >= center weight = 1, never 0) ----
    const float i0 = 1.f / n0, i1 = 1.f / n1;
    const int X = x0 + 2 * tx, Y = y0 + ty;
    float* ob = out + ((size_t)b * 32 + cg0) * HWp + (size_t)Y * W + X;
#pragma unroll
    for (int c = 0; c < 8; ++c) {
        float2 s;
        s.x = a0[c] * i0;
        s.y = a1[c] * i1;
        *(float2*)(ob + (size_t)c * HWp) = s;
    }
}

extern "C" void kernel_launch(void* const* d_in, const int* in_sizes, int n_in,
                              void* d_out, int out_size, void* d_ws, size_t ws_size,
                              hipStream_t stream) {
    const float* in    = (const float*)d_in[0];
    const float* guide = (const float*)d_in[1];
    const float* sigma = (const float*)d_in[2];
    float* out = (float*)d_out;
    dim3 grid(W / TW, H / TH, 2 * 4);   // z = batch*4 + channel-quarter
    bilateral_kernel<<<grid, dim3(256), 0, stream>>>(in, guide, sigma, out);
}

// Round 7
// 28.081 us; speedup vs baseline: 1.7682x; 1.1117x over previous
//
#include <hip/hip_runtime.h>

#define KS    7
#define RAD   3
#define TW    32            // tile width (output px)
#define TH    16            // tile height
#define HC    38            // TW + 2*RAD
#define HR    22            // TH + 2*RAD
#define NT    (HR*HC)       // 836 staging sites
#define PITCH 43            // physical row stride in col-units (max swz(37)=41, +pad)
#define H     256
#define W     256
#define HWp   (H*W)

typedef __fp16    h2raw __attribute__((ext_vector_type(2)));
typedef _Float16  f16x2 __attribute__((ext_vector_type(2)));

// skew: spreads stride-2 reads across bank groups
__device__ __forceinline__ int swz(int c) { return c + (c >> 3); }

__device__ __forceinline__ unsigned pk(float a, float b) {
    h2raw h = __builtin_amdgcn_cvt_pkrtz(a, b);
    return __builtin_bit_cast(unsigned, h);
}
__device__ __forceinline__ f16x2 pkh(float a, float b) {
    return __builtin_bit_cast(f16x2, __builtin_amdgcn_cvt_pkrtz(a, b));
}

#if __has_builtin(__builtin_amdgcn_fdot2)
__device__ __forceinline__ float fdot2(f16x2 a, f16x2 b, float c) {
    return __builtin_amdgcn_fdot2(a, b, c, false);
}
#else
__device__ __forceinline__ float fdot2(f16x2 a, f16x2 b, float c) {
    return c + (float)a.x * (float)b.x + (float)a.y * (float)b.y;
}
#endif

__global__ __launch_bounds__(256, 4)
void bilateral_kernel(const float* __restrict__ in,      // [B][32][H][W]
                      const float* __restrict__ guide,   // [B][3][H][W]
                      const float* __restrict__ sigma_p, // [1]
                      float* __restrict__ out)           // [B][32][H][W]
{
    __shared__ uint4 dt[HR * PITCH];     // input: 8ch fp16 per px (16B)
    __shared__ uint2 gt[HR * PITCH];     // guide: {x,y},{z,0} fp16 (8B)

    const int tid = threadIdx.x;
    const int tx  = tid & 15;            // x-pair index
    const int ty  = tid >> 4;            // y row (0..15)
    const int x0  = blockIdx.x * TW;
    const int y0  = blockIdx.y * TH;
    const int b   = blockIdx.z >> 2;     // batch
    const int cg0 = (blockIdx.z & 3) * 8;

    const float* gb  = guide + (size_t)b * 3 * HWp;
    const float* inb = in    + ((size_t)b * 32 + cg0) * HWp;

    const float sigma = sigma_p[0];
    const float isig2 = 1.0f / (sigma * sigma);
    float lnT[KS];                        // ln of spatial factor
#pragma unroll
    for (int i = 0; i < KS; ++i) {
        float r = (float)(i - RAD);
        lnT[i] = -0.5f * r * r * isig2;
    }

    // ---- stage: guide fp16 (uint2) + input 8ch fp16 (uint4), zero halo ----
#pragma unroll
    for (int it = 0; it < 4; ++it) {
        int idx = tid + it * 256;
        if (idx < NT) {
            int row = idx / HC;
            int col = idx - row * HC;
            int gy = y0 - RAD + row, gx = x0 - RAD + col;
            uint2 gv = make_uint2(0u, 0u);
            uint4 pv = make_uint4(0u, 0u, 0u, 0u);
            if (gy >= 0 && gy < H && gx >= 0 && gx < W) {
                int off = gy * W + gx;
                gv.x = pk(gb[off], gb[HWp + off]);
                gv.y = pk(gb[2 * HWp + off], 0.f);
                float v0 = inb[off],           v1 = inb[HWp + off];
                float v2 = inb[2 * HWp + off], v3 = inb[3 * HWp + off];
                float v4 = inb[4 * HWp + off], v5 = inb[5 * HWp + off];
                float v6 = inb[6 * HWp + off], v7 = inb[7 * HWp + off];
                pv.x = pk(v0, v1); pv.y = pk(v2, v3);
                pv.z = pk(v4, v5); pv.w = pk(v6, v7);
            }
            int a = row * PITCH + swz(col);
            gt[a] = gv;
            dt[a] = pv;
        }
    }
    __syncthreads();

    // ---- negated centers for this thread's 2 pixels (fp16 pairs) ----
    uint2 c0r = gt[(ty + RAD) * PITCH + swz(2 * tx + 3)];
    uint2 c1r = gt[(ty + RAD) * PITCH + swz(2 * tx + 4)];
    const f16x2 nc0xy = -__builtin_bit_cast(f16x2, c0r.x);
    const f16x2 nc0z  = -__builtin_bit_cast(f16x2, c0r.y);
    const f16x2 nc1xy = -__builtin_bit_cast(f16x2, c1r.x);
    const f16x2 nc1z  = -__builtin_bit_cast(f16x2, c1r.y);

    float n0 = 0.f, n1 = 0.f;
    float a0[8], a1[8];
#pragma unroll
    for (int c = 0; c < 8; ++c) { a0[c] = 0.f; a1[c] = 0.f; }

    // ---- fused weight+apply; fp16 row-accumulate, f32 flush per row ----
#pragma unroll
    for (int i = 0; i < KS; ++i) {
        const int base = (ty + i) * PITCH;
        uint2 gq[8];
        uint4 rq[8];
#pragma unroll
        for (int k = 0; k < 8; ++k) {
            int a = base + swz(2 * tx + k);
            gq[k] = gt[a];
            rq[k] = dt[a];
        }
        f16x2 A0[4], A1[4];
#pragma unroll
        for (int k = 0; k < 4; ++k) {
            A0[k] = (f16x2)0;
            A1[k] = (f16x2)0;
        }
#pragma unroll
        for (int dj = 0; dj < KS; ++dj) {
            const float lnE = lnT[i] + lnT[dj];
            // pixel 0: window col dj
            f16x2 gxy = __builtin_bit_cast(f16x2, gq[dj].x);
            f16x2 gz  = __builtin_bit_cast(f16x2, gq[dj].y);
            f16x2 dxy = gxy + nc0xy;
            f16x2 dz  = gz + nc0z;           // lane1 = 0
            float s0 = fdot2(dxy, dxy, fdot2(dz, dz, 0.f));
            float w0 = __expf(fmaf(s0, -0.5f, lnE));
            n0 += w0;
            f16x2 w0h = pkh(w0, w0);
            A0[0] = w0h * __builtin_bit_cast(f16x2, rq[dj].x) + A0[0];
            A0[1] = w0h * __builtin_bit_cast(f16x2, rq[dj].y) + A0[1];
            A0[2] = w0h * __builtin_bit_cast(f16x2, rq[dj].z) + A0[2];
            A0[3] = w0h * __builtin_bit_cast(f16x2, rq[dj].w) + A0[3];
            // pixel 1: window col dj+1
            gxy = __builtin_bit_cast(f16x2, gq[dj + 1].x);
            gz  = __builtin_bit_cast(f16x2, gq[dj + 1].y);
            dxy = gxy + nc1xy;
            dz  = gz + nc1z;
            float s1 = fdot2(dxy, dxy, fdot2(dz, dz, 0.f));
            float w1 = __expf(fmaf(s1, -0.5f, lnE));
            n1 += w1;
            f16x2 w1h = pkh(w1, w1);
            A1[0] = w1h * __builtin_bit_cast(f16x2, rq[dj + 1].x) + A1[0];
            A1[1] = w1h * __builtin_bit_cast(f16x2, rq[dj + 1].y) + A1[1];
            A1[2] = w1h * __builtin_bit_cast(f16x2, rq[dj + 1].z) + A1[2];
            A1[3] = w1h * __builtin_bit_cast(f16x2, rq[dj + 1].w) + A1[3];
        }
        // flush row accumulators to f32 (bounds fp16 chain at 7 adds)
#pragma unroll
        for (int k = 0; k < 4; ++k) {
            a0[2 * k]     += (float)A0[k].x;
            a0[2 * k + 1] += (float)A0[k].y;
            a1[2 * k]     += (float)A1[k].x;
            a1[2 * k + 1] += (float)A1[k].y;
        }
    }

    // ---- normalize + store (norm >= center weight = 1, never 0) ----
    const float i0 = 1.f / n0, i1 = 1.f / n1;
    const int X = x0 + 2 * tx, Y = y0 + ty;
    float* ob = out + ((size_t)b * 32 + cg0) * HWp + (size_t)Y * W + X;
#pragma unroll
    for (int c = 0; c < 8; ++c) {
        float2 s;
        s.x = a0[c] * i0;
        s.y = a1[c] * i1;
        *(float2*)(ob + (size_t)c * HWp) = s;
    }
}

extern "C" void kernel_launch(void* const* d_in, const int* in_sizes, int n_in,
                              void* d_out, int out_size, void* d_ws, size_t ws_size,
                              hipStream_t stream) {
    const float* in    = (const float*)d_in[0];
    const float* guide = (const float*)d_in[1];
    const float* sigma = (const float*)d_in[2];
    float* out = (float*)d_out;
    dim3 grid(W / TW, H / TH, 2 * 4);   // z = batch*4 + channel-quarter
    bilateral_kernel<<<grid, dim3(256), 0, stream>>>(in, guide, sigma, out);
}